// Round 8
// baseline (512.933 us; speedup 1.0000x reference)
//
#include <hip/hip_runtime.h>
#include <hip/hip_bf16.h>

#define N_NODES 50000
#define N_EDGES 800000
#define DIM 128
#define SCAN_BLOCKS ((N_NODES + 255) / 256)   // 196
#define NGROUPS (N_NODES / 16)                 // 3125 (exact)

typedef __attribute__((ext_vector_type(8))) short frag8;
typedef __attribute__((ext_vector_type(4))) float f32x4;

// fp32 -> bf16 bits (RNE)
__device__ __forceinline__ ushort f2b(float f){
  uint u = __float_as_uint(f);
  return (ushort)((u + 0x7fffu + ((u >> 16) & 1u)) >> 16);
}
__device__ __forceinline__ float b2f(ushort h){
  return __uint_as_float(((uint)h) << 16);
}

// ---------------- CSR build (per launch; graph-capture safe) ----------------

__global__ __launch_bounds__(256) void hist_k(
    const int* __restrict__ dst, int* __restrict__ deg)
{
  int e = blockIdx.x * 256 + threadIdx.x;
  if (e < N_EDGES) atomicAdd(deg + dst[e], 1);
}

__global__ __launch_bounds__(256) void scan_part_k(
    const int* __restrict__ deg, int* __restrict__ excl,
    int* __restrict__ blocksum)
{
  int t = threadIdx.x, lane = t & 63, w = t >> 6;
  int idx = blockIdx.x * 256 + t;
  int v = (idx < N_NODES) ? deg[idx] : 0;
  int inc = v;
  #pragma unroll
  for (int off = 1; off < 64; off <<= 1) {
    int y = __shfl_up(inc, off, 64);
    if (lane >= off) inc += y;
  }
  __shared__ int wsum[4];
  if (lane == 63) wsum[w] = inc;
  __syncthreads();
  int wpre = 0;
  #pragma unroll
  for (int i = 0; i < 4; i++) if (i < w) wpre += wsum[i];
  if (idx < N_NODES) excl[idx] = wpre + inc - v;
  if (t == 255) blocksum[blockIdx.x] = wpre + inc;
}

__global__ __launch_bounds__(256) void scan_tops_k(
    const int* __restrict__ blocksum, int* __restrict__ tops)
{
  int t = threadIdx.x, lane = t & 63, w = t >> 6;
  int v = (t < SCAN_BLOCKS) ? blocksum[t] : 0;
  int inc = v;
  #pragma unroll
  for (int off = 1; off < 64; off <<= 1) {
    int y = __shfl_up(inc, off, 64);
    if (lane >= off) inc += y;
  }
  __shared__ int wsum[4];
  if (lane == 63) wsum[w] = inc;
  __syncthreads();
  int wpre = 0;
  #pragma unroll
  for (int i = 0; i < 4; i++) if (i < w) wpre += wsum[i];
  if (t < SCAN_BLOCKS) tops[t] = wpre + inc - v;
}

__global__ __launch_bounds__(256) void scan_add_k(
    const int* __restrict__ excl, const int* __restrict__ tops,
    int* __restrict__ row_start, int* __restrict__ cursor)
{
  int idx = blockIdx.x * 256 + threadIdx.x;
  if (idx < N_NODES) {
    int r = excl[idx] + tops[blockIdx.x];
    row_start[idx] = r;
    cursor[idx] = r;
  }
  if (idx == 0) row_start[N_NODES] = N_EDGES;
}

__global__ __launch_bounds__(256) void scatter_k(
    const int* __restrict__ src, const int* __restrict__ dst,
    int* __restrict__ cursor, int* __restrict__ csr_src)
{
  int e = blockIdx.x * 256 + threadIdx.x;
  if (e >= N_EDGES) return;
  int pos = atomicAdd(cursor + dst[e], 1);
  csr_src[pos] = src[e];
}

// ---------------- fragment-layout prep ----------------
// A-frag layout (verified m89): lane holds A[m=lane&15][k=(lane>>4)*8+j], j=0..7.
// xa[(G*4 + C)*64 + lane][8]: G = node>>4, C = k-chunk of 32.
__global__ __launch_bounds__(256) void prep_x(
    const float* __restrict__ x, ushort* __restrict__ xah,
    ushort* __restrict__ xal)
{
  int unit = blockIdx.x * 4 + (threadIdx.x >> 6);
  if (unit >= NGROUPS * 4) return;
  int lane = threadIdx.x & 63;
  int G = unit >> 2, C = unit & 3;
  int m = lane & 15, q = lane >> 4;
  const float* p = x + (size_t)(G*16 + m)*DIM + C*32 + q*8;
  float v[8];
  *(float4*)(v)     = *(const float4*)p;
  *(float4*)(v + 4) = *(const float4*)(p + 4);
  ushort h[8], l[8];
  #pragma unroll
  for (int j = 0; j < 8; j++) {
    h[j] = f2b(v[j]);
    l[j] = f2b(v[j] - b2f(h[j]));
  }
  size_t off = ((size_t)unit*64 + lane)*8;
  *(frag8*)(xah + off) = *(frag8*)h;
  *(frag8*)(xal + off) = *(frag8*)l;
}

// B-frag: lane holds B[k=(lane>>4)*8+j][n=lane&15].
// wb[((layer*4 + C)*16 + g)*64 + lane][8]; combined dim: <128 -> Wl, else Wr.
__global__ __launch_bounds__(64) void prep_w(
    const float* __restrict__ Wl1, const float* __restrict__ Wr1,
    const float* __restrict__ Wl2, const float* __restrict__ Wr2,
    ushort* __restrict__ wbh, ushort* __restrict__ wbl)
{
  int bid = blockIdx.x;            // 2 layers * 4 C * 16 g = 128 blocks
  int layer = bid >> 6, rest = bid & 63;
  int C = rest >> 4, g = rest & 15;
  int lane = threadIdx.x;
  int m = lane & 15, q = lane >> 4;
  int dim = g*16 + m;
  const float* W = layer ? (dim < 128 ? Wl2 : Wr2) : (dim < 128 ? Wl1 : Wr1);
  int dcol = dim & 127;
  ushort h[8], l[8];
  #pragma unroll
  for (int j = 0; j < 8; j++) {
    int k = C*32 + q*8 + j;
    float v = W[(size_t)k*DIM + dcol];
    h[j] = f2b(v);
    l[j] = f2b(v - b2f(h[j]));
  }
  size_t off = ((size_t)bid*64 + lane)*8;
  *(frag8*)(wbh + off) = *(frag8*)h;
  *(frag8*)(wbl + off) = *(frag8*)l;
}

// ---------------- MFMA dual GEMM ----------------
// Wave = 16 nodes (group G) x 256 combined dims (16 tiles of 16x16).
// Split precision: C = Ah*Bh + Ah*Bl + Al*Bh (fp32 acc) ~= fp32 GEMM.
// No LDS; b-frags stream from L2 (128 KB working set per layer).
__global__ __launch_bounds__(256) void gemm_mfma(
    const ushort* __restrict__ xah, const ushort* __restrict__ xal,
    const ushort* __restrict__ wbh, const ushort* __restrict__ wbl,
    const float* __restrict__ bl, const float* __restrict__ br,
    float* __restrict__ xl, float* __restrict__ xr)
{
  int wv = threadIdx.x >> 6, lane = threadIdx.x & 63;
  int G = blockIdx.x * 4 + wv;
  if (G >= NGROUPS) return;

  f32x4 acc[16];
  #pragma unroll
  for (int g = 0; g < 16; g++) acc[g] = (f32x4)(0.f);

  #pragma unroll 1
  for (int C = 0; C < 4; C++) {
    size_t aoff = ((size_t)(G*4 + C)*64 + lane)*8;
    frag8 ah = *(const frag8*)(xah + aoff);
    frag8 al = *(const frag8*)(xal + aoff);
    #pragma unroll 4
    for (int g = 0; g < 16; g++) {
      size_t boff = ((size_t)(C*16 + g)*64 + lane)*8;
      frag8 bh = *(const frag8*)(wbh + boff);
      frag8 bo = *(const frag8*)(wbl + boff);
      acc[g] = __builtin_amdgcn_mfma_f32_16x16x32_bf16(ah, bh, acc[g], 0, 0, 0);
      acc[g] = __builtin_amdgcn_mfma_f32_16x16x32_bf16(ah, bo, acc[g], 0, 0, 0);
      acc[g] = __builtin_amdgcn_mfma_f32_16x16x32_bf16(al, bh, acc[g], 0, 0, 0);
    }
  }

  // C/D layout: col = lane&15, row = (lane>>4)*4 + reg (row = node-in-group)
  int q = lane >> 4, nin = lane & 15;
  #pragma unroll
  for (int g = 0; g < 16; g++) {
    int dim = g*16 + nin;
    bool left = dim < 128;
    int dcol = dim & 127;
    float bv = left ? bl[dcol] : br[dcol];
    float* outp = left ? xl : xr;
    #pragma unroll
    for (int r = 0; r < 4; r++) {
      int node = G*16 + q*4 + r;
      outp[(size_t)node*DIM + dcol] = acc[g][r] + bv;
    }
  }
}

// ---------------- fused edge phase: 32 lanes/node, 2 nodes/wave ------------
// OUTMODE 0: write fp32 rows (final output). OUTMODE 1: write bf16 hi/lo
// A-fragment layout (input of next layer's gemm_mfma).
template<int OUTMODE>
__global__ __launch_bounds__(256) void gat_gather(
    const float* __restrict__ xl, const float* __restrict__ xr,
    const int* __restrict__ row_start, const int* __restrict__ csr_src,
    const float* __restrict__ att, const float* __restrict__ bias,
    float* __restrict__ out, ushort* __restrict__ oh, ushort* __restrict__ ol)
{
  int wave = (blockIdx.x * 256 + threadIdx.x) >> 6;
  int lane = threadIdx.x & 63;
  int half = lane >> 5;
  int hl = lane & 31;
  int node = wave * 2 + half;
  bool valid = node < N_NODES;
  int nc = valid ? node : (N_NODES - 1);
  int r0 = row_start[nc], r1 = row_start[nc + 1];
  int deg = valid ? (r1 - r0) : 0;
  int last = r0 + deg - 1;
  int dmax = max(deg, __shfl_xor(deg, 32, 64));

  float4 xrv = *(const float4*)(xr + (size_t)nc*DIM + hl*4);
  float4 av  = *(const float4*)(att + hl*4);
  float m = -INFINITY, l = 0.f;
  float4 acc = make_float4(0.f, 0.f, 0.f, 0.f);

  for (int t = 0; t < dmax; t += 8) {
    float4 v[8];
    float p[8];
    #pragma unroll
    for (int j = 0; j < 8; j++) {
      int rr = r0 + t + j;
      int rc = rr <= last ? rr : last;
      rc = rc >= 0 ? rc : 0;
      int si = csr_src[rc];
      v[j] = *(const float4*)(xl + (size_t)si*DIM + hl*4);
    }
    #pragma unroll
    for (int j = 0; j < 8; j++) {
      float s0 = v[j].x + xrv.x, s1 = v[j].y + xrv.y;
      float s2 = v[j].z + xrv.z, s3 = v[j].w + xrv.w;
      s0 = s0 > 0.f ? s0 : 0.2f*s0;
      s1 = s1 > 0.f ? s1 : 0.2f*s1;
      s2 = s2 > 0.f ? s2 : 0.2f*s2;
      s3 = s3 > 0.f ? s3 : 0.2f*s3;
      p[j] = av.x*s0 + av.y*s1 + av.z*s2 + av.w*s3;
    }
    #pragma unroll
    for (int o = 1; o <= 16; o <<= 1) {
      #pragma unroll
      for (int j = 0; j < 8; j++) p[j] += __shfl_xor(p[j], o, 64);
    }
    #pragma unroll
    for (int j = 0; j < 8; j++) if (t + j >= deg) p[j] = -INFINITY;
    float pmax = p[0];
    #pragma unroll
    for (int j = 1; j < 8; j++) pmax = fmaxf(pmax, p[j]);
    float mn = fmaxf(m, pmax);
    float sc = (mn == -INFINITY) ? 0.f : __expf(m - mn);
    l *= sc; acc.x *= sc; acc.y *= sc; acc.z *= sc; acc.w *= sc;
    #pragma unroll
    for (int j = 0; j < 8; j++) {
      float w = (t + j < deg) ? __expf(p[j] - mn) : 0.f;
      l += w;
      acc.x = fmaf(w, v[j].x, acc.x);
      acc.y = fmaf(w, v[j].y, acc.y);
      acc.z = fmaf(w, v[j].z, acc.z);
      acc.w = fmaf(w, v[j].w, acc.w);
    }
    m = mn;
  }

  if (valid) {
    float denom = fmaxf(l, 1e-16f);
    float4 bv = *(const float4*)(bias + hl*4);
    float ov[4];
    ov[0] = fmaxf(acc.x / denom + bv.x, 0.f);
    ov[1] = fmaxf(acc.y / denom + bv.y, 0.f);
    ov[2] = fmaxf(acc.z / denom + bv.z, 0.f);
    ov[3] = fmaxf(acc.w / denom + bv.w, 0.f);
    if (OUTMODE == 0) {
      *(float4*)(out + (size_t)node*DIM + hl*4) = *(float4*)ov;
    } else {
      // frag layout: G=node>>4, C=hl>>3, lane L=((hl>>1)&3)*16+(node&15), j=(hl&1)*4..
      ushort h4[4], l4[4];
      #pragma unroll
      for (int t2 = 0; t2 < 4; t2++) {
        h4[t2] = f2b(ov[t2]);
        l4[t2] = f2b(ov[t2] - b2f(h4[t2]));
      }
      int G = node >> 4, C = hl >> 3;
      int L = ((hl >> 1) & 3) * 16 + (node & 15);
      size_t off = (((size_t)(G*4 + C)*64) + L)*8 + (hl & 1)*4;
      *(ushort4*)(oh + off) = *(ushort4*)h4;
      *(ushort4*)(ol + off) = *(ushort4*)l4;
    }
  }
}

extern "C" void kernel_launch(void* const* d_in, const int* in_sizes, int n_in,
                              void* d_out, int out_size, void* d_ws, size_t ws_size,
                              hipStream_t stream)
{
  const float* node_fts = (const float*)d_in[0];
  const int*  edge_index = (const int*)d_in[1];
  const float* Wl1 = (const float*)d_in[2];
  const float* bl1 = (const float*)d_in[3];
  const float* Wr1 = (const float*)d_in[4];
  const float* br1 = (const float*)d_in[5];
  const float* att1 = (const float*)d_in[6];
  const float* bias1 = (const float*)d_in[7];
  const float* Wl2 = (const float*)d_in[8];
  const float* bl2 = (const float*)d_in[9];
  const float* Wr2 = (const float*)d_in[10];
  const float* br2 = (const float*)d_in[11];
  const float* att2 = (const float*)d_in[12];
  const float* bias2 = (const float*)d_in[13];
  const int* src = edge_index;
  const int* dst = edge_index + N_EDGES;

  char* ws = (char*)d_ws;
  float* xl  = (float*)ws;                 ws += (size_t)N_NODES*DIM*4;
  float* xr  = (float*)ws;                 ws += (size_t)N_NODES*DIM*4;
  ushort* xah = (ushort*)ws;               ws += (size_t)N_NODES*DIM*2;
  ushort* xal = (ushort*)ws;               ws += (size_t)N_NODES*DIM*2;
  ushort* wbh = (ushort*)ws;               ws += 2*4*16*64*8*2;
  ushort* wbl = (ushort*)ws;               ws += 2*4*16*64*8*2;
  int* deg       = (int*)ws;               ws += N_NODES*4;
  int* row_start = (int*)ws;               ws += (N_NODES+1)*4;
  int* cursor    = (int*)ws;               ws += N_NODES*4;
  int* csr_src   = (int*)ws;               ws += (size_t)N_EDGES*4;
  int* excl      = (int*)ws;               ws += N_NODES*4;
  int* blocksum  = (int*)ws;               ws += SCAN_BLOCKS*4;
  int* tops      = (int*)ws;

  const int W_LAYER = 4*16*64*8;           // ushorts per layer of wb

  int eb = (N_EDGES + 255) / 256;
  int gemm_blocks = (NGROUPS + 3) / 4;
  int gather_waves = (N_NODES + 1) / 2;
  int gather_blocks = (gather_waves + 3) / 4;

  // ---- CSR build ----
  hipMemsetAsync(deg, 0, N_NODES * sizeof(int), stream);
  hist_k<<<eb, 256, 0, stream>>>(dst, deg);
  scan_part_k<<<SCAN_BLOCKS, 256, 0, stream>>>(deg, excl, blocksum);
  scan_tops_k<<<1, 256, 0, stream>>>(blocksum, tops);
  scan_add_k<<<SCAN_BLOCKS, 256, 0, stream>>>(excl, tops, row_start, cursor);
  scatter_k<<<eb, 256, 0, stream>>>(src, dst, cursor, csr_src);

  // ---- fragment prep ----
  prep_w<<<128, 64, 0, stream>>>(Wl1, Wr1, Wl2, Wr2, wbh, wbl);
  prep_x<<<(NGROUPS*4 + 3)/4, 256, 0, stream>>>(node_fts, xah, xal);

  // ---- layer 1 ----
  gemm_mfma<<<gemm_blocks, 256, 0, stream>>>(xah, xal, wbh, wbl, bl1, br1, xl, xr);
  gat_gather<1><<<gather_blocks, 256, 0, stream>>>(xl, xr, row_start, csr_src,
                                                   att1, bias1, nullptr, xah, xal);
  // ---- layer 2 ----
  gemm_mfma<<<gemm_blocks, 256, 0, stream>>>(xah, xal, wbh + W_LAYER, wbl + W_LAYER,
                                             bl2, br2, xl, xr);
  gat_gather<0><<<gather_blocks, 256, 0, stream>>>(xl, xr, row_start, csr_src,
                                                   att2, bias2, (float*)d_out,
                                                   nullptr, nullptr);
}

// Round 9
// 510.500 us; speedup vs baseline: 1.0048x; 1.0048x over previous
//
#include <hip/hip_runtime.h>
#include <hip/hip_bf16.h>

#define N_NODES 50000
#define N_EDGES 800000
#define DIM 128
#define SCAN_BLOCKS ((N_NODES + 255) / 256)   // 196
#define NGROUPS (N_NODES / 16)                 // 3125 (exact)
#define LROW 260                               // LDS row stride (floats): 16B-aligned, 2-way-free

typedef __attribute__((ext_vector_type(8))) short frag8;
typedef __attribute__((ext_vector_type(4))) float f32x4;

// fp32 -> bf16 bits (RNE)
__device__ __forceinline__ ushort f2b(float f){
  uint u = __float_as_uint(f);
  return (ushort)((u + 0x7fffu + ((u >> 16) & 1u)) >> 16);
}
__device__ __forceinline__ float b2f(ushort h){
  return __uint_as_float(((uint)h) << 16);
}

// ---------------- CSR build (per launch; graph-capture safe) ----------------

__global__ __launch_bounds__(256) void hist_k(
    const int* __restrict__ dst, int* __restrict__ deg)
{
  int e = blockIdx.x * 256 + threadIdx.x;
  if (e < N_EDGES) atomicAdd(deg + dst[e], 1);
}

__global__ __launch_bounds__(256) void scan_part_k(
    const int* __restrict__ deg, int* __restrict__ excl,
    int* __restrict__ blocksum)
{
  int t = threadIdx.x, lane = t & 63, w = t >> 6;
  int idx = blockIdx.x * 256 + t;
  int v = (idx < N_NODES) ? deg[idx] : 0;
  int inc = v;
  #pragma unroll
  for (int off = 1; off < 64; off <<= 1) {
    int y = __shfl_up(inc, off, 64);
    if (lane >= off) inc += y;
  }
  __shared__ int wsum[4];
  if (lane == 63) wsum[w] = inc;
  __syncthreads();
  int wpre = 0;
  #pragma unroll
  for (int i = 0; i < 4; i++) if (i < w) wpre += wsum[i];
  if (idx < N_NODES) excl[idx] = wpre + inc - v;
  if (t == 255) blocksum[blockIdx.x] = wpre + inc;
}

__global__ __launch_bounds__(256) void scan_tops_k(
    const int* __restrict__ blocksum, int* __restrict__ tops)
{
  int t = threadIdx.x, lane = t & 63, w = t >> 6;
  int v = (t < SCAN_BLOCKS) ? blocksum[t] : 0;
  int inc = v;
  #pragma unroll
  for (int off = 1; off < 64; off <<= 1) {
    int y = __shfl_up(inc, off, 64);
    if (lane >= off) inc += y;
  }
  __shared__ int wsum[4];
  if (lane == 63) wsum[w] = inc;
  __syncthreads();
  int wpre = 0;
  #pragma unroll
  for (int i = 0; i < 4; i++) if (i < w) wpre += wsum[i];
  if (t < SCAN_BLOCKS) tops[t] = wpre + inc - v;
}

__global__ __launch_bounds__(256) void scan_add_k(
    const int* __restrict__ excl, const int* __restrict__ tops,
    int* __restrict__ row_start, int* __restrict__ cursor)
{
  int idx = blockIdx.x * 256 + threadIdx.x;
  if (idx < N_NODES) {
    int r = excl[idx] + tops[blockIdx.x];
    row_start[idx] = r;
    cursor[idx] = r;
  }
  if (idx == 0) row_start[N_NODES] = N_EDGES;
}

__global__ __launch_bounds__(256) void scatter_k(
    const int* __restrict__ src, const int* __restrict__ dst,
    int* __restrict__ cursor, int* __restrict__ csr_src)
{
  int e = blockIdx.x * 256 + threadIdx.x;
  if (e >= N_EDGES) return;
  int pos = atomicAdd(cursor + dst[e], 1);
  csr_src[pos] = src[e];
}

// ---------------- fragment-layout prep ----------------
// A-frag layout: lane holds A[m=lane&15][k=(lane>>4)*8+j], j=0..7.
// xa[(G*4 + C)*64 + lane][8]: G = node>>4, C = k-chunk of 32.
__global__ __launch_bounds__(256) void prep_x(
    const float* __restrict__ x, ushort* __restrict__ xah,
    ushort* __restrict__ xal)
{
  int unit = blockIdx.x * 4 + (threadIdx.x >> 6);
  if (unit >= NGROUPS * 4) return;
  int lane = threadIdx.x & 63;
  int G = unit >> 2, C = unit & 3;
  int m = lane & 15, q = lane >> 4;
  const float* p = x + (size_t)(G*16 + m)*DIM + C*32 + q*8;
  float v[8];
  *(float4*)(v)     = *(const float4*)p;
  *(float4*)(v + 4) = *(const float4*)(p + 4);
  ushort h[8], l[8];
  #pragma unroll
  for (int j = 0; j < 8; j++) {
    h[j] = f2b(v[j]);
    l[j] = f2b(v[j] - b2f(h[j]));
  }
  size_t off = ((size_t)unit*64 + lane)*8;
  *(frag8*)(xah + off) = *(frag8*)h;
  *(frag8*)(xal + off) = *(frag8*)l;
}

// B-frag: lane holds B[k=(lane>>4)*8+j][n=lane&15].
// wb[((layer*4 + C)*16 + g)*64 + lane][8]; combined dim: <128 -> Wl, else Wr.
__global__ __launch_bounds__(64) void prep_w(
    const float* __restrict__ Wl1, const float* __restrict__ Wr1,
    const float* __restrict__ Wl2, const float* __restrict__ Wr2,
    ushort* __restrict__ wbh, ushort* __restrict__ wbl)
{
  int bid = blockIdx.x;            // 2 layers * 4 C * 16 g = 128 blocks
  int layer = bid >> 6, rest = bid & 63;
  int C = rest >> 4, g = rest & 15;
  int lane = threadIdx.x;
  int m = lane & 15, q = lane >> 4;
  int dim = g*16 + m;
  const float* W = layer ? (dim < 128 ? Wl2 : Wr2) : (dim < 128 ? Wl1 : Wr1);
  int dcol = dim & 127;
  ushort h[8], l[8];
  #pragma unroll
  for (int j = 0; j < 8; j++) {
    int k = C*32 + q*8 + j;
    float v = W[(size_t)k*DIM + dcol];
    h[j] = f2b(v);
    l[j] = f2b(v - b2f(h[j]));
  }
  size_t off = ((size_t)bid*64 + lane)*8;
  *(frag8*)(wbh + off) = *(frag8*)h;
  *(frag8*)(wbl + off) = *(frag8*)l;
}

// ---------------- MFMA dual GEMM ----------------
// Wave = 16 nodes (group G) x 256 combined dims (16 tiles of 16x16).
// Split precision: C = Ah*Bh + Ah*Bl + Al*Bh (fp32 acc) ~= fp32 GEMM.
// Epilogue: per-wave LDS transpose -> wave-contiguous float4 stores
// (scalar C/D-layout stores caused 5.6x HBM write amplification in R8).
__global__ __launch_bounds__(256) void gemm_mfma(
    const ushort* __restrict__ xah, const ushort* __restrict__ xal,
    const ushort* __restrict__ wbh, const ushort* __restrict__ wbl,
    const float* __restrict__ bl, const float* __restrict__ br,
    float* __restrict__ xl, float* __restrict__ xr)
{
  __shared__ float lds[4][16*LROW];   // 65 KB, per-wave private slice
  int wv = threadIdx.x >> 6, lane = threadIdx.x & 63;
  int G = blockIdx.x * 4 + wv;
  if (G >= NGROUPS) return;

  f32x4 acc[16];
  #pragma unroll
  for (int g = 0; g < 16; g++) acc[g] = (f32x4)(0.f);

  #pragma unroll 1
  for (int C = 0; C < 4; C++) {
    size_t aoff = ((size_t)(G*4 + C)*64 + lane)*8;
    frag8 ah = *(const frag8*)(xah + aoff);
    frag8 al = *(const frag8*)(xal + aoff);
    #pragma unroll 4
    for (int g = 0; g < 16; g++) {
      size_t boff = ((size_t)(C*16 + g)*64 + lane)*8;
      frag8 bh = *(const frag8*)(wbh + boff);
      frag8 bo = *(const frag8*)(wbl + boff);
      acc[g] = __builtin_amdgcn_mfma_f32_16x16x32_bf16(ah, bh, acc[g], 0, 0, 0);
      acc[g] = __builtin_amdgcn_mfma_f32_16x16x32_bf16(ah, bo, acc[g], 0, 0, 0);
      acc[g] = __builtin_amdgcn_mfma_f32_16x16x32_bf16(al, bh, acc[g], 0, 0, 0);
    }
  }

  // C/D layout: col = lane&15 (dim-in-tile), row = (lane>>4)*4 + reg (node).
  // Stage to LDS [node][dim], then read back coalesced.
  float* wlds = lds[wv];
  int q = lane >> 4, nin = lane & 15;
  #pragma unroll
  for (int g = 0; g < 16; g++) {
    #pragma unroll
    for (int r = 0; r < 4; r++)
      wlds[(q*4 + r)*LROW + g*16 + nin] = acc[g][r];
  }
  // same-wave LDS dependency only; compiler inserts lgkmcnt wait

  int dstart = lane * 4;
  bool left = dstart < 128;
  int dcol = dstart & 127;
  const float* B = left ? bl : br;
  float* outp = left ? xl : xr;
  float4 bv = *(const float4*)(B + dcol);
  #pragma unroll
  for (int i = 0; i < 16; i++) {
    float4 v = *(const float4*)(wlds + i*LROW + dstart);
    int node = G*16 + i;
    float4 o = make_float4(v.x + bv.x, v.y + bv.y, v.z + bv.z, v.w + bv.w);
    *(float4*)(outp + (size_t)node*DIM + dcol) = o;
  }
}

// ---------------- fused edge phase: 32 lanes/node, 2 nodes/wave ------------
__global__ __launch_bounds__(256) void gat_gather(
    const float* __restrict__ xl, const float* __restrict__ xr,
    const int* __restrict__ row_start, const int* __restrict__ csr_src,
    const float* __restrict__ att, const float* __restrict__ bias,
    float* __restrict__ out)
{
  int wave = (blockIdx.x * 256 + threadIdx.x) >> 6;
  int lane = threadIdx.x & 63;
  int half = lane >> 5;
  int hl = lane & 31;
  int node = wave * 2 + half;
  bool valid = node < N_NODES;
  int nc = valid ? node : (N_NODES - 1);
  int r0 = row_start[nc], r1 = row_start[nc + 1];
  int deg = valid ? (r1 - r0) : 0;
  int last = r0 + deg - 1;
  int dmax = max(deg, __shfl_xor(deg, 32, 64));

  float4 xrv = *(const float4*)(xr + (size_t)nc*DIM + hl*4);
  float4 av  = *(const float4*)(att + hl*4);
  float m = -INFINITY, l = 0.f;
  float4 acc = make_float4(0.f, 0.f, 0.f, 0.f);

  for (int t = 0; t < dmax; t += 8) {
    float4 v[8];
    float p[8];
    #pragma unroll
    for (int j = 0; j < 8; j++) {
      int rr = r0 + t + j;
      int rc = rr <= last ? rr : last;
      rc = rc >= 0 ? rc : 0;
      int si = csr_src[rc];
      v[j] = *(const float4*)(xl + (size_t)si*DIM + hl*4);
    }
    #pragma unroll
    for (int j = 0; j < 8; j++) {
      float s0 = v[j].x + xrv.x, s1 = v[j].y + xrv.y;
      float s2 = v[j].z + xrv.z, s3 = v[j].w + xrv.w;
      s0 = s0 > 0.f ? s0 : 0.2f*s0;
      s1 = s1 > 0.f ? s1 : 0.2f*s1;
      s2 = s2 > 0.f ? s2 : 0.2f*s2;
      s3 = s3 > 0.f ? s3 : 0.2f*s3;
      p[j] = av.x*s0 + av.y*s1 + av.z*s2 + av.w*s3;
    }
    #pragma unroll
    for (int o = 1; o <= 16; o <<= 1) {
      #pragma unroll
      for (int j = 0; j < 8; j++) p[j] += __shfl_xor(p[j], o, 64);
    }
    #pragma unroll
    for (int j = 0; j < 8; j++) if (t + j >= deg) p[j] = -INFINITY;
    float pmax = p[0];
    #pragma unroll
    for (int j = 1; j < 8; j++) pmax = fmaxf(pmax, p[j]);
    float mn = fmaxf(m, pmax);
    float sc = (mn == -INFINITY) ? 0.f : __expf(m - mn);
    l *= sc; acc.x *= sc; acc.y *= sc; acc.z *= sc; acc.w *= sc;
    #pragma unroll
    for (int j = 0; j < 8; j++) {
      float w = (t + j < deg) ? __expf(p[j] - mn) : 0.f;
      l += w;
      acc.x = fmaf(w, v[j].x, acc.x);
      acc.y = fmaf(w, v[j].y, acc.y);
      acc.z = fmaf(w, v[j].z, acc.z);
      acc.w = fmaf(w, v[j].w, acc.w);
    }
    m = mn;
  }

  if (valid) {
    float denom = fmaxf(l, 1e-16f);
    float4 bv = *(const float4*)(bias + hl*4);
    float4 ov;
    ov.x = fmaxf(acc.x / denom + bv.x, 0.f);
    ov.y = fmaxf(acc.y / denom + bv.y, 0.f);
    ov.z = fmaxf(acc.z / denom + bv.z, 0.f);
    ov.w = fmaxf(acc.w / denom + bv.w, 0.f);
    *(float4*)(out + (size_t)node*DIM + hl*4) = ov;
  }
}

extern "C" void kernel_launch(void* const* d_in, const int* in_sizes, int n_in,
                              void* d_out, int out_size, void* d_ws, size_t ws_size,
                              hipStream_t stream)
{
  const float* node_fts = (const float*)d_in[0];
  const int*  edge_index = (const int*)d_in[1];
  const float* Wl1 = (const float*)d_in[2];
  const float* bl1 = (const float*)d_in[3];
  const float* Wr1 = (const float*)d_in[4];
  const float* br1 = (const float*)d_in[5];
  const float* att1 = (const float*)d_in[6];
  const float* bias1 = (const float*)d_in[7];
  const float* Wl2 = (const float*)d_in[8];
  const float* bl2 = (const float*)d_in[9];
  const float* Wr2 = (const float*)d_in[10];
  const float* br2 = (const float*)d_in[11];
  const float* att2 = (const float*)d_in[12];
  const float* bias2 = (const float*)d_in[13];
  const int* src = edge_index;
  const int* dst = edge_index + N_EDGES;

  char* ws = (char*)d_ws;
  float* xl  = (float*)ws;                 ws += (size_t)N_NODES*DIM*4;
  float* xr  = (float*)ws;                 ws += (size_t)N_NODES*DIM*4;
  float* h   = (float*)ws;                 ws += (size_t)N_NODES*DIM*4;
  ushort* xah = (ushort*)ws;               ws += (size_t)N_NODES*DIM*2;
  ushort* xal = (ushort*)ws;               ws += (size_t)N_NODES*DIM*2;
  ushort* wbh = (ushort*)ws;               ws += 2*4*16*64*8*2;
  ushort* wbl = (ushort*)ws;               ws += 2*4*16*64*8*2;
  int* deg       = (int*)ws;               ws += N_NODES*4;
  int* row_start = (int*)ws;               ws += (N_NODES+1)*4;
  int* cursor    = (int*)ws;               ws += N_NODES*4;
  int* csr_src   = (int*)ws;               ws += (size_t)N_EDGES*4;
  int* excl      = (int*)ws;               ws += N_NODES*4;
  int* blocksum  = (int*)ws;               ws += SCAN_BLOCKS*4;
  int* tops      = (int*)ws;

  const int W_LAYER = 4*16*64*8;           // ushorts per layer of wb

  int eb = (N_EDGES + 255) / 256;
  int gemm_blocks = (NGROUPS + 3) / 4;
  int prep_blocks = (NGROUPS*4 + 3) / 4;
  int gather_waves = (N_NODES + 1) / 2;
  int gather_blocks = (gather_waves + 3) / 4;

  // ---- CSR build ----
  hipMemsetAsync(deg, 0, N_NODES * sizeof(int), stream);
  hist_k<<<eb, 256, 0, stream>>>(dst, deg);
  scan_part_k<<<SCAN_BLOCKS, 256, 0, stream>>>(deg, excl, blocksum);
  scan_tops_k<<<1, 256, 0, stream>>>(blocksum, tops);
  scan_add_k<<<SCAN_BLOCKS, 256, 0, stream>>>(excl, tops, row_start, cursor);
  scatter_k<<<eb, 256, 0, stream>>>(src, dst, cursor, csr_src);

  // ---- fragment prep ----
  prep_w<<<128, 64, 0, stream>>>(Wl1, Wr1, Wl2, Wr2, wbh, wbl);
  prep_x<<<prep_blocks, 256, 0, stream>>>(node_fts, xah, xal);

  // ---- layer 1 ----
  gemm_mfma<<<gemm_blocks, 256, 0, stream>>>(xah, xal, wbh, wbl, bl1, br1, xl, xr);
  gat_gather<<<gather_blocks, 256, 0, stream>>>(xl, xr, row_start, csr_src,
                                                att1, bias1, h);
  // ---- layer 2 ----
  prep_x<<<prep_blocks, 256, 0, stream>>>(h, xah, xal);
  gemm_mfma<<<gemm_blocks, 256, 0, stream>>>(xah, xal, wbh + W_LAYER, wbl + W_LAYER,
                                             bl2, br2, xl, xr);
  gat_gather<<<gather_blocks, 256, 0, stream>>>(xl, xr, row_start, csr_src,
                                                att2, bias2, (float*)d_out);
}

// Round 10
// 383.247 us; speedup vs baseline: 1.3384x; 1.3320x over previous
//
#include <hip/hip_runtime.h>
#include <hip/hip_bf16.h>

#define N_NODES 50000
#define N_EDGES 800000
#define DIM 128
#define SCAN_BLOCKS ((N_NODES + 255) / 256)   // 196
#define NGROUPS (N_NODES / 16)                 // 3125 (exact)
#define LROW 260                               // LDS row stride (floats)

typedef __attribute__((ext_vector_type(8))) short frag8;
typedef __attribute__((ext_vector_type(4))) float f32x4;

// fp32 -> bf16 bits (RNE)
__device__ __forceinline__ ushort f2b(float f){
  uint u = __float_as_uint(f);
  return (ushort)((u + 0x7fffu + ((u >> 16) & 1u)) >> 16);
}
__device__ __forceinline__ float b2f(ushort h){
  return __uint_as_float(((uint)h) << 16);
}

// ---------------- CSR build (per launch; graph-capture safe) ----------------

__global__ __launch_bounds__(256) void hist_k(
    const int* __restrict__ dst, int* __restrict__ deg)
{
  int e = blockIdx.x * 256 + threadIdx.x;
  if (e < N_EDGES) atomicAdd(deg + dst[e], 1);
}

__global__ __launch_bounds__(256) void scan_part_k(
    const int* __restrict__ deg, int* __restrict__ excl,
    int* __restrict__ blocksum)
{
  int t = threadIdx.x, lane = t & 63, w = t >> 6;
  int idx = blockIdx.x * 256 + t;
  int v = (idx < N_NODES) ? deg[idx] : 0;
  int inc = v;
  #pragma unroll
  for (int off = 1; off < 64; off <<= 1) {
    int y = __shfl_up(inc, off, 64);
    if (lane >= off) inc += y;
  }
  __shared__ int wsum[4];
  if (lane == 63) wsum[w] = inc;
  __syncthreads();
  int wpre = 0;
  #pragma unroll
  for (int i = 0; i < 4; i++) if (i < w) wpre += wsum[i];
  if (idx < N_NODES) excl[idx] = wpre + inc - v;
  if (t == 255) blocksum[blockIdx.x] = wpre + inc;
}

__global__ __launch_bounds__(256) void scan_tops_k(
    const int* __restrict__ blocksum, int* __restrict__ tops)
{
  int t = threadIdx.x, lane = t & 63, w = t >> 6;
  int v = (t < SCAN_BLOCKS) ? blocksum[t] : 0;
  int inc = v;
  #pragma unroll
  for (int off = 1; off < 64; off <<= 1) {
    int y = __shfl_up(inc, off, 64);
    if (lane >= off) inc += y;
  }
  __shared__ int wsum[4];
  if (lane == 63) wsum[w] = inc;
  __syncthreads();
  int wpre = 0;
  #pragma unroll
  for (int i = 0; i < 4; i++) if (i < w) wpre += wsum[i];
  if (t < SCAN_BLOCKS) tops[t] = wpre + inc - v;
}

__global__ __launch_bounds__(256) void scan_add_k(
    const int* __restrict__ excl, const int* __restrict__ tops,
    int* __restrict__ row_start, int* __restrict__ cursor)
{
  int idx = blockIdx.x * 256 + threadIdx.x;
  if (idx < N_NODES) {
    int r = excl[idx] + tops[blockIdx.x];
    row_start[idx] = r;
    cursor[idx] = r;
  }
  if (idx == 0) row_start[N_NODES] = N_EDGES;
}

__global__ __launch_bounds__(256) void scatter_k(
    const int* __restrict__ src, const int* __restrict__ dst,
    int* __restrict__ cursor, int* __restrict__ csr_src)
{
  int e = blockIdx.x * 256 + threadIdx.x;
  if (e >= N_EDGES) return;
  int pos = atomicAdd(cursor + dst[e], 1);
  csr_src[pos] = src[e];
}

// ---------------- fragment-layout prep ----------------
// A-frag layout: lane holds A[m=lane&15][k=(lane>>4)*8+j], j=0..7.
// xa[(G*4 + C)*64 + lane][8]: G = node>>4, C = k-chunk of 32.
__global__ __launch_bounds__(256) void prep_x(
    const float* __restrict__ x, ushort* __restrict__ xah,
    ushort* __restrict__ xal)
{
  int unit = blockIdx.x * 4 + (threadIdx.x >> 6);
  if (unit >= NGROUPS * 4) return;
  int lane = threadIdx.x & 63;
  int G = unit >> 2, C = unit & 3;
  int m = lane & 15, q = lane >> 4;
  const float* p = x + (size_t)(G*16 + m)*DIM + C*32 + q*8;
  float v[8];
  *(float4*)(v)     = *(const float4*)p;
  *(float4*)(v + 4) = *(const float4*)(p + 4);
  ushort h[8], l[8];
  #pragma unroll
  for (int j = 0; j < 8; j++) {
    h[j] = f2b(v[j]);
    l[j] = f2b(v[j] - b2f(h[j]));
  }
  size_t off = ((size_t)unit*64 + lane)*8;
  *(frag8*)(xah + off) = *(frag8*)h;
  *(frag8*)(xal + off) = *(frag8*)l;
}

// B-frag: lane holds B[k=(lane>>4)*8+j][n=lane&15].
// wb[((layer*4 + C)*16 + g)*64 + lane][8]; combined dim: <128 -> Wl, else Wr.
__global__ __launch_bounds__(64) void prep_w(
    const float* __restrict__ Wl1, const float* __restrict__ Wr1,
    const float* __restrict__ Wl2, const float* __restrict__ Wr2,
    ushort* __restrict__ wbh, ushort* __restrict__ wbl)
{
  int bid = blockIdx.x;            // 2 layers * 4 C * 16 g = 128 blocks
  int layer = bid >> 6, rest = bid & 63;
  int C = rest >> 4, g = rest & 15;
  int lane = threadIdx.x;
  int m = lane & 15, q = lane >> 4;
  int dim = g*16 + m;
  const float* W = layer ? (dim < 128 ? Wl2 : Wr2) : (dim < 128 ? Wl1 : Wr1);
  int dcol = dim & 127;
  ushort h[8], l[8];
  #pragma unroll
  for (int j = 0; j < 8; j++) {
    int k = C*32 + q*8 + j;
    float v = W[(size_t)k*DIM + dcol];
    h[j] = f2b(v);
    l[j] = f2b(v - b2f(h[j]));
  }
  size_t off = ((size_t)bid*64 + lane)*8;
  *(frag8*)(wbh + off) = *(frag8*)h;
  *(frag8*)(wbl + off) = *(frag8*)l;
}

// ---------------- MFMA dual GEMM ----------------
// Wave = 16 nodes (group G) x 256 combined dims (16 tiles of 16x16).
// Split precision: C = Ah*Bh + Ah*Bl + Al*Bh (fp32 acc) ~= fp32 GEMM.
// g-loop FULLY unrolled: dynamic acc[g] indexing spilled the accumulator
// array to scratch in R8/R9 (VGPR_Count 44! ~270 MB of phantom HBM traffic).
__global__ __launch_bounds__(256) void gemm_mfma(
    const ushort* __restrict__ xah, const ushort* __restrict__ xal,
    const ushort* __restrict__ wbh, const ushort* __restrict__ wbl,
    const float* __restrict__ bl, const float* __restrict__ br,
    float* __restrict__ xl, float* __restrict__ xr)
{
  __shared__ float lds[4][16*LROW];   // 65 KB, per-wave private slice
  int wv = threadIdx.x >> 6, lane = threadIdx.x & 63;
  int G = blockIdx.x * 4 + wv;
  if (G >= NGROUPS) return;

  f32x4 acc[16];
  #pragma unroll
  for (int g = 0; g < 16; g++) acc[g] = (f32x4)(0.f);

  #pragma unroll 1
  for (int C = 0; C < 4; C++) {
    size_t aoff = ((size_t)(G*4 + C)*64 + lane)*8;
    frag8 ah = *(const frag8*)(xah + aoff);
    frag8 al = *(const frag8*)(xal + aoff);
    #pragma unroll
    for (int g = 0; g < 16; g++) {
      size_t boff = ((size_t)(C*16 + g)*64 + lane)*8;
      frag8 bh = *(const frag8*)(wbh + boff);
      frag8 bo = *(const frag8*)(wbl + boff);
      acc[g] = __builtin_amdgcn_mfma_f32_16x16x32_bf16(ah, bh, acc[g], 0, 0, 0);
      acc[g] = __builtin_amdgcn_mfma_f32_16x16x32_bf16(ah, bo, acc[g], 0, 0, 0);
      acc[g] = __builtin_amdgcn_mfma_f32_16x16x32_bf16(al, bh, acc[g], 0, 0, 0);
    }
  }

  // C/D layout: col = lane&15 (dim-in-tile), row = (lane>>4)*4 + reg (node).
  // Stage to LDS [node][dim], then read back coalesced.
  float* wlds = lds[wv];
  int q = lane >> 4, nin = lane & 15;
  #pragma unroll
  for (int g = 0; g < 16; g++) {
    #pragma unroll
    for (int r = 0; r < 4; r++)
      wlds[(q*4 + r)*LROW + g*16 + nin] = acc[g][r];
  }
  // same-wave LDS dependency only; compiler inserts lgkmcnt wait

  int dstart = lane * 4;
  bool left = dstart < 128;
  int dcol = dstart & 127;
  const float* B = left ? bl : br;
  float* outp = left ? xl : xr;
  float4 bv = *(const float4*)(B + dcol);
  #pragma unroll
  for (int i = 0; i < 16; i++) {
    float4 v = *(const float4*)(wlds + i*LROW + dstart);
    int node = G*16 + i;
    float4 o = make_float4(v.x + bv.x, v.y + bv.y, v.z + bv.z, v.w + bv.w);
    *(float4*)(outp + (size_t)node*DIM + dcol) = o;
  }
}

// ---------------- fused edge phase: 32 lanes/node, 2 nodes/wave ------------
__global__ __launch_bounds__(256) void gat_gather(
    const float* __restrict__ xl, const float* __restrict__ xr,
    const int* __restrict__ row_start, const int* __restrict__ csr_src,
    const float* __restrict__ att, const float* __restrict__ bias,
    float* __restrict__ out)
{
  int wave = (blockIdx.x * 256 + threadIdx.x) >> 6;
  int lane = threadIdx.x & 63;
  int half = lane >> 5;
  int hl = lane & 31;
  int node = wave * 2 + half;
  bool valid = node < N_NODES;
  int nc = valid ? node : (N_NODES - 1);
  int r0 = row_start[nc], r1 = row_start[nc + 1];
  int deg = valid ? (r1 - r0) : 0;
  int last = r0 + deg - 1;
  int dmax = max(deg, __shfl_xor(deg, 32, 64));

  float4 xrv = *(const float4*)(xr + (size_t)nc*DIM + hl*4);
  float4 av  = *(const float4*)(att + hl*4);
  float m = -INFINITY, l = 0.f;
  float4 acc = make_float4(0.f, 0.f, 0.f, 0.f);

  for (int t = 0; t < dmax; t += 8) {
    float4 v[8];
    float p[8];
    #pragma unroll
    for (int j = 0; j < 8; j++) {
      int rr = r0 + t + j;
      int rc = rr <= last ? rr : last;
      rc = rc >= 0 ? rc : 0;
      int si = csr_src[rc];
      v[j] = *(const float4*)(xl + (size_t)si*DIM + hl*4);
    }
    #pragma unroll
    for (int j = 0; j < 8; j++) {
      float s0 = v[j].x + xrv.x, s1 = v[j].y + xrv.y;
      float s2 = v[j].z + xrv.z, s3 = v[j].w + xrv.w;
      s0 = s0 > 0.f ? s0 : 0.2f*s0;
      s1 = s1 > 0.f ? s1 : 0.2f*s1;
      s2 = s2 > 0.f ? s2 : 0.2f*s2;
      s3 = s3 > 0.f ? s3 : 0.2f*s3;
      p[j] = av.x*s0 + av.y*s1 + av.z*s2 + av.w*s3;
    }
    #pragma unroll
    for (int o = 1; o <= 16; o <<= 1) {
      #pragma unroll
      for (int j = 0; j < 8; j++) p[j] += __shfl_xor(p[j], o, 64);
    }
    #pragma unroll
    for (int j = 0; j < 8; j++) if (t + j >= deg) p[j] = -INFINITY;
    float pmax = p[0];
    #pragma unroll
    for (int j = 1; j < 8; j++) pmax = fmaxf(pmax, p[j]);
    float mn = fmaxf(m, pmax);
    float sc = (mn == -INFINITY) ? 0.f : __expf(m - mn);
    l *= sc; acc.x *= sc; acc.y *= sc; acc.z *= sc; acc.w *= sc;
    #pragma unroll
    for (int j = 0; j < 8; j++) {
      float w = (t + j < deg) ? __expf(p[j] - mn) : 0.f;
      l += w;
      acc.x = fmaf(w, v[j].x, acc.x);
      acc.y = fmaf(w, v[j].y, acc.y);
      acc.z = fmaf(w, v[j].z, acc.z);
      acc.w = fmaf(w, v[j].w, acc.w);
    }
    m = mn;
  }

  if (valid) {
    float denom = fmaxf(l, 1e-16f);
    float4 bv = *(const float4*)(bias + hl*4);
    float4 ov;
    ov.x = fmaxf(acc.x / denom + bv.x, 0.f);
    ov.y = fmaxf(acc.y / denom + bv.y, 0.f);
    ov.z = fmaxf(acc.z / denom + bv.z, 0.f);
    ov.w = fmaxf(acc.w / denom + bv.w, 0.f);
    *(float4*)(out + (size_t)node*DIM + hl*4) = ov;
  }
}

extern "C" void kernel_launch(void* const* d_in, const int* in_sizes, int n_in,
                              void* d_out, int out_size, void* d_ws, size_t ws_size,
                              hipStream_t stream)
{
  const float* node_fts = (const float*)d_in[0];
  const int*  edge_index = (const int*)d_in[1];
  const float* Wl1 = (const float*)d_in[2];
  const float* bl1 = (const float*)d_in[3];
  const float* Wr1 = (const float*)d_in[4];
  const float* br1 = (const float*)d_in[5];
  const float* att1 = (const float*)d_in[6];
  const float* bias1 = (const float*)d_in[7];
  const float* Wl2 = (const float*)d_in[8];
  const float* bl2 = (const float*)d_in[9];
  const float* Wr2 = (const float*)d_in[10];
  const float* br2 = (const float*)d_in[11];
  const float* att2 = (const float*)d_in[12];
  const float* bias2 = (const float*)d_in[13];
  const int* src = edge_index;
  const int* dst = edge_index + N_EDGES;

  char* ws = (char*)d_ws;
  float* xl  = (float*)ws;                 ws += (size_t)N_NODES*DIM*4;
  float* xr  = (float*)ws;                 ws += (size_t)N_NODES*DIM*4;
  float* h   = (float*)ws;                 ws += (size_t)N_NODES*DIM*4;
  ushort* xah = (ushort*)ws;               ws += (size_t)N_NODES*DIM*2;
  ushort* xal = (ushort*)ws;               ws += (size_t)N_NODES*DIM*2;
  ushort* wbh = (ushort*)ws;               ws += 2*4*16*64*8*2;
  ushort* wbl = (ushort*)ws;               ws += 2*4*16*64*8*2;
  int* deg       = (int*)ws;               ws += N_NODES*4;
  int* row_start = (int*)ws;               ws += (N_NODES+1)*4;
  int* cursor    = (int*)ws;               ws += N_NODES*4;
  int* csr_src   = (int*)ws;               ws += (size_t)N_EDGES*4;
  int* excl      = (int*)ws;               ws += N_NODES*4;
  int* blocksum  = (int*)ws;               ws += SCAN_BLOCKS*4;
  int* tops      = (int*)ws;

  const int W_LAYER = 4*16*64*8;           // ushorts per layer of wb

  int eb = (N_EDGES + 255) / 256;
  int gemm_blocks = (NGROUPS + 3) / 4;
  int prep_blocks = (NGROUPS*4 + 3) / 4;
  int gather_waves = (N_NODES + 1) / 2;
  int gather_blocks = (gather_waves + 3) / 4;

  // ---- CSR build ----
  hipMemsetAsync(deg, 0, N_NODES * sizeof(int), stream);
  hist_k<<<eb, 256, 0, stream>>>(dst, deg);
  scan_part_k<<<SCAN_BLOCKS, 256, 0, stream>>>(deg, excl, blocksum);
  scan_tops_k<<<1, 256, 0, stream>>>(blocksum, tops);
  scan_add_k<<<SCAN_BLOCKS, 256, 0, stream>>>(excl, tops, row_start, cursor);
  scatter_k<<<eb, 256, 0, stream>>>(src, dst, cursor, csr_src);

  // ---- fragment prep ----
  prep_w<<<128, 64, 0, stream>>>(Wl1, Wr1, Wl2, Wr2, wbh, wbl);
  prep_x<<<prep_blocks, 256, 0, stream>>>(node_fts, xah, xal);

  // ---- layer 1 ----
  gemm_mfma<<<gemm_blocks, 256, 0, stream>>>(xah, xal, wbh, wbl, bl1, br1, xl, xr);
  gat_gather<<<gather_blocks, 256, 0, stream>>>(xl, xr, row_start, csr_src,
                                                att1, bias1, h);
  // ---- layer 2 ----
  prep_x<<<prep_blocks, 256, 0, stream>>>(h, xah, xal);
  gemm_mfma<<<gemm_blocks, 256, 0, stream>>>(xah, xal, wbh + W_LAYER, wbl + W_LAYER,
                                             bl2, br2, xl, xr);
  gat_gather<<<gather_blocks, 256, 0, stream>>>(xl, xr, row_start, csr_src,
                                                att2, bias2, (float*)d_out);
}